// Round 1
// baseline (1992.569 us; speedup 1.0000x reference)
//
#include <hip/hip_runtime.h>
#include <hip/hip_bf16.h>
#include <math.h>

#define B_  16
#define S_  626
#define H_  768
#define NH_ 12
#define DH_ 64
#define BH_ (B_*NH_)          // 192
#define M_  (B_*S_)           // 10016
#define SM1 (S_-1)            // 625

// ---------------------------------------------------------------------------
// Generic C = A(MxK) @ W(KxN) + bias(N), fp32.
// 128x128 block tile, 8x8 per thread (2x2 blocks of 4x4 at +-64 offsets),
// K-chunk 32. A staged transposed As[k][m] (stride 132), B row-major Bs[k][n].
// Fragment reads: 4x ds_read_b128 per kk -> 64 FMA (4x the old FMA:LDS ratio).
// MODE 0: C row-major (M x N).
// MODE 1: head-scatter epilogue: row=(b,s), col=(h,d) -> out[((b*NH+h)*S+s)*DH+d]
// ---------------------------------------------------------------------------
template<int MODE>
__global__ __launch_bounds__(256) void gemm_bias(
        const float* __restrict__ A, const float* __restrict__ W,
        const float* __restrict__ bias, float* __restrict__ out,
        int M, int N, int K) {
    __shared__ float As[32][132];   // [k][m] transposed A tile, padded stride
    __shared__ float Bs[32][128];   // [k][n]
    const int tid = threadIdx.x;
    const int tx = tid & 15, ty = tid >> 4;
    const int rowBase = blockIdx.y * 128;
    const int colBase = blockIdx.x * 128;
    float c[2][2][4][4] = {};       // [rowGroup][colGroup][i][j]

    for (int k0 = 0; k0 < K; k0 += 32) {
        // A tile: 128 rows x 32 k. float4 per thread along k (coalesced),
        // scatter into transposed As.
        #pragma unroll
        for (int l = 0; l < 4; ++l) {
            int idx = tid + l * 256;          // 0..1023
            int kk = (idx & 7) << 2;          // 0,4,...,28
            int m  = idx >> 3;                // 0..127
            int row = rowBase + m;
            float4 v4 = make_float4(0.f, 0.f, 0.f, 0.f);
            if (row < M) v4 = *(const float4*)&A[(size_t)row * K + k0 + kk];
            As[kk + 0][m] = v4.x;
            As[kk + 1][m] = v4.y;
            As[kk + 2][m] = v4.z;
            As[kk + 3][m] = v4.w;
        }
        // B tile: 32 k x 128 n, float4 along n (coalesced, contiguous LDS write)
        #pragma unroll
        for (int l = 0; l < 4; ++l) {
            int idx = tid + l * 256;
            int n  = (idx & 31) << 2;
            int kk = idx >> 5;
            *(float4*)&Bs[kk][n] =
                *(const float4*)&W[(size_t)(k0 + kk) * N + colBase + n];
        }
        __syncthreads();
        #pragma unroll 8
        for (int kk = 0; kk < 32; ++kk) {
            float a[2][4], b[2][4];
            *(float4*)a[0] = *(const float4*)&As[kk][ty * 4];        // rows ty*4..+3
            *(float4*)a[1] = *(const float4*)&As[kk][64 + ty * 4];   // rows 64+ty*4..
            *(float4*)b[0] = *(const float4*)&Bs[kk][tx * 4];        // cols tx*4..+3
            *(float4*)b[1] = *(const float4*)&Bs[kk][64 + tx * 4];
            #pragma unroll
            for (int rg = 0; rg < 2; ++rg)
                #pragma unroll
                for (int cg = 0; cg < 2; ++cg)
                    #pragma unroll
                    for (int i = 0; i < 4; ++i)
                        #pragma unroll
                        for (int j = 0; j < 4; ++j)
                            c[rg][cg][i][j] += a[rg][i] * b[cg][j];
        }
        __syncthreads();
    }

    #pragma unroll
    for (int rg = 0; rg < 2; ++rg) {
        #pragma unroll
        for (int i = 0; i < 4; ++i) {
            int row = rowBase + rg * 64 + ty * 4 + i;
            if (row >= M) continue;
            #pragma unroll
            for (int cg = 0; cg < 2; ++cg) {
                int col = colBase + cg * 64 + tx * 4;
                float4 val;
                val.x = c[rg][cg][i][0] + bias[col + 0];
                val.y = c[rg][cg][i][1] + bias[col + 1];
                val.z = c[rg][cg][i][2] + bias[col + 2];
                val.w = c[rg][cg][i][3] + bias[col + 3];
                if (MODE == 0) {
                    *(float4*)&out[(size_t)row * N + col] = val;
                } else {
                    int b_ = row / S_, s_ = row - b_ * S_;
                    int h_ = col >> 6, d_ = col & 63;   // DH=64, tx*4+3 stays in one head
                    *(float4*)&out[(((size_t)(b_ * NH_ + h_) * S_ + s_) << 6) + d_] = val;
                }
            }
        }
    }
}

// ---------------------------------------------------------------------------
// scores[bh, q, k] = (Q[bh,q,:] . K[bh,k,:]) * 0.125   (DH=64)
// 64x64 output tile, full K=64 staged transposed [d][row], stride 68.
// (unchanged from prior round; upgrade pending counters)
// ---------------------------------------------------------------------------
__global__ void scores_kernel(const float* __restrict__ q, const float* __restrict__ k,
                              float* __restrict__ scores) {
    const int bh = blockIdx.z;
    const int qbase = blockIdx.y * 64;
    const int kbase = blockIdx.x * 64;
    __shared__ float Qs[64][68];   // [d][qrow]
    __shared__ float Ks[64][68];   // [d][krow]
    const int tid = threadIdx.x;
    const float* qb = q + (size_t)bh * S_ * DH_;
    const float* kb = k + (size_t)bh * S_ * DH_;
    #pragma unroll
    for (int l = 0; l < 16; ++l) {
        int idx = tid + l * 256;
        int d = idx & 63, r = idx >> 6;       // consecutive lanes: consecutive d (coalesced)
        Qs[d][r] = (qbase + r < S_) ? qb[((size_t)(qbase + r) << 6) + d] : 0.f;
        Ks[d][r] = (kbase + r < S_) ? kb[((size_t)(kbase + r) << 6) + d] : 0.f;
    }
    __syncthreads();
    const int tx = tid & 15, ty = tid >> 4;
    float c[4][4] = {};
    #pragma unroll 4
    for (int d = 0; d < 64; ++d) {
        float a[4], b[4];
        *(float4*)a = *(const float4*)&Qs[d][ty * 4];
        *(float4*)b = *(const float4*)&Ks[d][tx * 4];
        #pragma unroll
        for (int i = 0; i < 4; ++i)
            #pragma unroll
            for (int j = 0; j < 4; ++j) c[i][j] += a[i] * b[j];
    }
    #pragma unroll
    for (int i = 0; i < 4; ++i) {
        int qi = qbase + ty * 4 + i;
        if (qi >= S_) continue;
        float* row = scores + ((size_t)bh * S_ + qi) * S_;
        #pragma unroll
        for (int j = 0; j < 4; ++j) {
            int ki = kbase + tx * 4 + j;
            if (ki < S_) row[ki] = c[i][j] * 0.125f;
        }
    }
}

// ---------------------------------------------------------------------------
// Row-0 special case: max over row0, then +max*0.25 where mask_full < 0.5.
// ---------------------------------------------------------------------------
__global__ void row0_kernel(float* __restrict__ scores, const float* __restrict__ mask) {
    const int bh = blockIdx.x;
    const int b = bh / NH_;
    float* row = scores + (size_t)bh * S_ * S_;   // row 0
    __shared__ float red[256];
    const int tid = threadIdx.x;
    float m = -INFINITY;
    for (int k = tid; k < S_; k += 256) m = fmaxf(m, row[k]);
    red[tid] = m;
    __syncthreads();
    for (int s = 128; s > 0; s >>= 1) {
        if (tid < s) red[tid] = fmaxf(red[tid], red[tid + s]);
        __syncthreads();
    }
    const float mx = red[0];
    for (int k = tid; k < S_; k += 256) {
        float mf = (k == 0) ? 0.f : mask[(size_t)b * SM1 + k - 1];
        if (mf < 0.5f) row[k] += mx * 0.25f;
    }
}

// ---------------------------------------------------------------------------
// Fused softmax + ctx. One block per (q-tile of 64, bh).
// Sweep 1: per-row max & sum(exp) with the row held in registers (10 vals/lane),
//          snapshots adjusted col0 for sm2.
// Sweep 2: re-read raw scores (L2-warm), convert to probs, write probs in place
//          (weights output), accumulate ctx = probs @ V with 64x64 tiling.
// Eliminates the separate softmax pass: saves one full 300MB read + 300MB write.
// ---------------------------------------------------------------------------
__global__ __launch_bounds__(256) void softmax_ctx_kernel(
        float* __restrict__ scores,      // in: raw scores; out: probs (weights)
        const float* __restrict__ v,
        float* __restrict__ ctx,         // (B,S,H) layout
        float* __restrict__ col0) {
    const int bh = blockIdx.y;
    const int qbase = blockIdx.x * 64;
    const int b = bh / NH_, h = bh - b * NH_;
    __shared__ float Ps[32][68];   // [k][q]
    __shared__ float Vs[32][64];   // [k][d]
    __shared__ float rmax[64], rinv[64];
    const int tid = threadIdx.x;
    const int lane = tid & 63, wid = tid >> 6;
    float* sb = scores + (size_t)bh * S_ * S_;

    // ---- Sweep 1: row max + sum(exp), col0 snapshot ----
    for (int r = wid; r < 64; r += 4) {
        int q = qbase + r;
        if (q >= S_) continue;
        const float* row = sb + (size_t)q * S_;
        float vals[10];
        float mx = -INFINITY;
        #pragma unroll
        for (int i = 0; i < 10; ++i) {
            int k = lane + i * 64;
            vals[i] = (k < S_) ? row[k] : -INFINITY;
            mx = fmaxf(mx, vals[i]);
        }
        #pragma unroll
        for (int off = 32; off > 0; off >>= 1) mx = fmaxf(mx, __shfl_xor(mx, off, 64));
        float sum = 0.f;
        #pragma unroll
        for (int i = 0; i < 10; ++i)
            sum += (lane + i * 64 < S_) ? expf(vals[i] - mx) : 0.f;
        #pragma unroll
        for (int off = 32; off > 0; off >>= 1) sum += __shfl_xor(sum, off, 64);
        if (lane == 0) {
            rmax[r] = mx;
            rinv[r] = 1.f / sum;
            col0[(size_t)bh * S_ + q] = vals[0];
        }
    }
    __syncthreads();

    // ---- Sweep 2: probs on the fly, write probs, accumulate ctx ----
    const int tx = tid & 15, ty = tid >> 4;
    float c[4][4] = {};
    const float* vb = v + (size_t)bh * S_ * DH_;
    for (int k0 = 0; k0 < S_; k0 += 32) {
        #pragma unroll
        for (int l = 0; l < 8; ++l) {
            int idx = tid + l * 256;
            int kk = idx & 31, r = idx >> 5;
            int q = qbase + r, k2 = k0 + kk;
            float p = 0.f;
            if (q < S_ && k2 < S_) {
                float s = sb[(size_t)q * S_ + k2];
                p = expf(s - rmax[r]) * rinv[r];
                sb[(size_t)q * S_ + k2] = p;       // weights output (in place)
            }
            Ps[kk][r] = p;
        }
        #pragma unroll
        for (int l = 0; l < 8; ++l) {
            int idx = tid + l * 256;
            int d = idx & 63, r = idx >> 6;
            int k2 = k0 + r;
            Vs[r][d] = (k2 < S_) ? vb[((size_t)k2 << 6) + d] : 0.f;
        }
        __syncthreads();
        #pragma unroll
        for (int kk = 0; kk < 32; ++kk) {
            float a[4], bb[4];
            *(float4*)a  = *(const float4*)&Ps[kk][ty * 4];
            *(float4*)bb = *(const float4*)&Vs[kk][tx * 4];
            #pragma unroll
            for (int i = 0; i < 4; ++i)
                #pragma unroll
                for (int j = 0; j < 4; ++j) c[i][j] += a[i] * bb[j];
        }
        __syncthreads();
    }
    #pragma unroll
    for (int i = 0; i < 4; ++i) {
        int qq = qbase + ty * 4 + i;
        if (qq >= S_) continue;
        *(float4*)&ctx[((size_t)(b * S_ + qq)) * H_ + h * DH_ + tx * 4] = *(float4*)c[i];
    }
}

// ---------------------------------------------------------------------------
// sm2[bh, q] = softmax over q of col0[bh, :].
// ---------------------------------------------------------------------------
__global__ void sm2_kernel(const float* __restrict__ col0, float* __restrict__ out) {
    const int bh = blockIdx.x;
    const float* c = col0 + (size_t)bh * S_;
    __shared__ float red[256];
    const int tid = threadIdx.x;
    float m = -INFINITY;
    for (int q = tid; q < S_; q += 256) m = fmaxf(m, c[q]);
    red[tid] = m;
    __syncthreads();
    for (int s = 128; s > 0; s >>= 1) {
        if (tid < s) red[tid] = fmaxf(red[tid], red[tid + s]);
        __syncthreads();
    }
    const float mx = red[0];
    __syncthreads();
    float sum = 0.f;
    for (int q = tid; q < S_; q += 256) sum += expf(c[q] - mx);
    red[tid] = sum;
    __syncthreads();
    for (int s = 128; s > 0; s >>= 1) {
        if (tid < s) red[tid] += red[tid + s];
        __syncthreads();
    }
    const float inv = 1.f / red[0];
    for (int q = tid; q < S_; q += 256) out[(size_t)bh * S_ + q] = expf(c[q] - mx) * inv;
}

// ---------------------------------------------------------------------------
extern "C" void kernel_launch(void* const* d_in, const int* in_sizes, int n_in,
                              void* d_out, int out_size, void* d_ws, size_t ws_size,
                              hipStream_t stream) {
    const float* hs   = (const float*)d_in[0];
    const float* mask = (const float*)d_in[1];
    const float* Wq   = (const float*)d_in[2];
    const float* bq   = (const float*)d_in[3];
    const float* Wk   = (const float*)d_in[4];
    const float* bk   = (const float*)d_in[5];
    const float* Wv   = (const float*)d_in[6];
    const float* bv   = (const float*)d_in[7];
    const float* Wo   = (const float*)d_in[8];
    const float* bo   = (const float*)d_in[9];

    float* out     = (float*)d_out;                              // (B,S,H)
    float* weights = out + (size_t)B_ * S_ * H_;                 // (B,NH,S,S)
    float* sm2     = weights + (size_t)BH_ * S_ * S_;            // (B,NH,S)

    float* ws    = (float*)d_ws;
    const size_t headSz = (size_t)BH_ * S_ * DH_;                // 7,692,288
    float* q_ws  = ws;
    float* k_ws  = q_ws + headSz;
    float* v_ws  = k_ws + headSz;
    float* col0  = v_ws + headSz;                                // BH*S floats
    float* ctx_ws = q_ws;                                        // Q dead after scores

    dim3 gemmGrid(6, 79);       // N=768/128, ceil(10016/128)
    gemm_bias<1><<<gemmGrid, 256, 0, stream>>>(hs, Wq, bq, q_ws, M_, H_, H_);
    gemm_bias<1><<<gemmGrid, 256, 0, stream>>>(hs, Wk, bk, k_ws, M_, H_, H_);
    gemm_bias<1><<<gemmGrid, 256, 0, stream>>>(hs, Wv, bv, v_ws, M_, H_, H_);

    scores_kernel<<<dim3(10, 10, BH_), 256, 0, stream>>>(q_ws, k_ws, weights);
    row0_kernel<<<BH_, 256, 0, stream>>>(weights, mask);
    softmax_ctx_kernel<<<dim3(10, BH_), 256, 0, stream>>>(weights, v_ws, ctx_ws, col0);
    sm2_kernel<<<BH_, 256, 0, stream>>>(col0, sm2);

    gemm_bias<0><<<gemmGrid, 256, 0, stream>>>(ctx_ws, Wo, bo, out, M_, H_, H_);
}

// Round 2
// 1552.204 us; speedup vs baseline: 1.2837x; 1.2837x over previous
//
#include <hip/hip_runtime.h>
#include <hip/hip_bf16.h>
#include <math.h>

#define B_  16
#define S_  626
#define H_  768
#define NH_ 12
#define DH_ 64
#define BH_ (B_*NH_)          // 192
#define M_  (B_*S_)           // 10016
#define SM1 (S_-1)            // 625

// ---------------------------------------------------------------------------
// Generic C = A(MxK) @ W(KxN) + bias(N), fp32.
// 128x128 block tile, 8x8 per thread (2x2 blocks of 4x4 at +-64 offsets),
// K-chunk 32.
// MODE 0: C row-major (M x N).
// MODE 1: head-scatter epilogue: row=(b,s), col=(h,d) -> out[((b*NH+h)*S+s)*DH+d]
// ---------------------------------------------------------------------------
template<int MODE>
__global__ __launch_bounds__(256) void gemm_bias(
        const float* __restrict__ A, const float* __restrict__ W,
        const float* __restrict__ bias, float* __restrict__ out,
        int M, int N, int K) {
    __shared__ float As[32][132];   // [k][m] transposed A tile, padded stride
    __shared__ float Bs[32][128];   // [k][n]
    const int tid = threadIdx.x;
    const int tx = tid & 15, ty = tid >> 4;
    const int rowBase = blockIdx.y * 128;
    const int colBase = blockIdx.x * 128;
    float c[2][2][4][4] = {};       // [rowGroup][colGroup][i][j]

    for (int k0 = 0; k0 < K; k0 += 32) {
        #pragma unroll
        for (int l = 0; l < 4; ++l) {
            int idx = tid + l * 256;          // 0..1023
            int kk = (idx & 7) << 2;          // 0,4,...,28
            int m  = idx >> 3;                // 0..127
            int row = rowBase + m;
            float4 v4 = make_float4(0.f, 0.f, 0.f, 0.f);
            if (row < M) v4 = *(const float4*)&A[(size_t)row * K + k0 + kk];
            As[kk + 0][m] = v4.x;
            As[kk + 1][m] = v4.y;
            As[kk + 2][m] = v4.z;
            As[kk + 3][m] = v4.w;
        }
        #pragma unroll
        for (int l = 0; l < 4; ++l) {
            int idx = tid + l * 256;
            int n  = (idx & 31) << 2;
            int kk = idx >> 5;
            *(float4*)&Bs[kk][n] =
                *(const float4*)&W[(size_t)(k0 + kk) * N + colBase + n];
        }
        __syncthreads();
        #pragma unroll 8
        for (int kk = 0; kk < 32; ++kk) {
            float a[2][4], b[2][4];
            *(float4*)a[0] = *(const float4*)&As[kk][ty * 4];
            *(float4*)a[1] = *(const float4*)&As[kk][64 + ty * 4];
            *(float4*)b[0] = *(const float4*)&Bs[kk][tx * 4];
            *(float4*)b[1] = *(const float4*)&Bs[kk][64 + tx * 4];
            #pragma unroll
            for (int rg = 0; rg < 2; ++rg)
                #pragma unroll
                for (int cg = 0; cg < 2; ++cg)
                    #pragma unroll
                    for (int i = 0; i < 4; ++i)
                        #pragma unroll
                        for (int j = 0; j < 4; ++j)
                            c[rg][cg][i][j] += a[rg][i] * b[cg][j];
        }
        __syncthreads();
    }

    #pragma unroll
    for (int rg = 0; rg < 2; ++rg) {
        #pragma unroll
        for (int i = 0; i < 4; ++i) {
            int row = rowBase + rg * 64 + ty * 4 + i;
            if (row >= M) continue;
            #pragma unroll
            for (int cg = 0; cg < 2; ++cg) {
                int col = colBase + cg * 64 + tx * 4;
                float4 val;
                val.x = c[rg][cg][i][0] + bias[col + 0];
                val.y = c[rg][cg][i][1] + bias[col + 1];
                val.z = c[rg][cg][i][2] + bias[col + 2];
                val.w = c[rg][cg][i][3] + bias[col + 3];
                if (MODE == 0) {
                    *(float4*)&out[(size_t)row * N + col] = val;
                } else {
                    int b_ = row / S_, s_ = row - b_ * S_;
                    int h_ = col >> 6, d_ = col & 63;
                    *(float4*)&out[(((size_t)(b_ * NH_ + h_) * S_ + s_) << 6) + d_] = val;
                }
            }
        }
    }
}

// ---------------------------------------------------------------------------
// scores[bh, q, k] = (Q[bh,q,:] . K[bh,k,:]) * 0.125   (DH=64)
// NEW: 128x128 output tile, 8x8 per thread, K chunked by 32.
// 32 FMA : 4 b128-reads per kk per thread (was 16:2 on a 64 tile).
// ---------------------------------------------------------------------------
__global__ __launch_bounds__(256) void scores_kernel(
        const float* __restrict__ q, const float* __restrict__ k,
        float* __restrict__ scores) {
    const int bh = blockIdx.z;
    const int qbase = blockIdx.y * 128;
    const int kbase = blockIdx.x * 128;
    __shared__ float Qs[32][132];   // [d][qrow]
    __shared__ float Ks[32][132];   // [d][krow]
    const int tid = threadIdx.x;
    const int tx = tid & 15, ty = tid >> 4;
    const float* qb = q + (size_t)bh * S_ * DH_;
    const float* kb = k + (size_t)bh * S_ * DH_;
    float c[2][2][4][4] = {};

    for (int k0 = 0; k0 < DH_; k0 += 32) {
        #pragma unroll
        for (int l = 0; l < 4; ++l) {
            int idx = tid + l * 256;          // 0..1023
            int kk4 = (idx & 7) << 2;         // 0,4,...,28
            int m   = idx >> 3;               // 0..127
            float4 v4 = make_float4(0.f, 0.f, 0.f, 0.f);
            if (qbase + m < S_)
                v4 = *(const float4*)&qb[((size_t)(qbase + m) << 6) + k0 + kk4];
            Qs[kk4 + 0][m] = v4.x; Qs[kk4 + 1][m] = v4.y;
            Qs[kk4 + 2][m] = v4.z; Qs[kk4 + 3][m] = v4.w;
            float4 w4 = make_float4(0.f, 0.f, 0.f, 0.f);
            if (kbase + m < S_)
                w4 = *(const float4*)&kb[((size_t)(kbase + m) << 6) + k0 + kk4];
            Ks[kk4 + 0][m] = w4.x; Ks[kk4 + 1][m] = w4.y;
            Ks[kk4 + 2][m] = w4.z; Ks[kk4 + 3][m] = w4.w;
        }
        __syncthreads();
        #pragma unroll 8
        for (int kk = 0; kk < 32; ++kk) {
            float a[2][4], b[2][4];
            *(float4*)a[0] = *(const float4*)&Qs[kk][ty * 4];
            *(float4*)a[1] = *(const float4*)&Qs[kk][64 + ty * 4];
            *(float4*)b[0] = *(const float4*)&Ks[kk][tx * 4];
            *(float4*)b[1] = *(const float4*)&Ks[kk][64 + tx * 4];
            #pragma unroll
            for (int rg = 0; rg < 2; ++rg)
                #pragma unroll
                for (int cg = 0; cg < 2; ++cg)
                    #pragma unroll
                    for (int i = 0; i < 4; ++i)
                        #pragma unroll
                        for (int j = 0; j < 4; ++j)
                            c[rg][cg][i][j] += a[rg][i] * b[cg][j];
        }
        __syncthreads();
    }

    #pragma unroll
    for (int rg = 0; rg < 2; ++rg) {
        #pragma unroll
        for (int i = 0; i < 4; ++i) {
            int qi = qbase + rg * 64 + ty * 4 + i;
            if (qi >= S_) continue;
            float* row = scores + ((size_t)bh * S_ + qi) * S_;
            #pragma unroll
            for (int cg = 0; cg < 2; ++cg) {
                int ki = kbase + cg * 64 + tx * 4;
                if (ki + 3 < S_) {
                    float4 w;
                    w.x = c[rg][cg][i][0] * 0.125f;
                    w.y = c[rg][cg][i][1] * 0.125f;
                    w.z = c[rg][cg][i][2] * 0.125f;
                    w.w = c[rg][cg][i][3] * 0.125f;
                    *(float4*)&row[ki] = w;
                } else {
                    #pragma unroll
                    for (int j = 0; j < 4; ++j)
                        if (ki + j < S_) row[ki + j] = c[rg][cg][i][j] * 0.125f;
                }
            }
        }
    }
}

// ---------------------------------------------------------------------------
// Row-0 special case: max over row0, then +max*0.25 where mask_full < 0.5.
// ---------------------------------------------------------------------------
__global__ void row0_kernel(float* __restrict__ scores, const float* __restrict__ mask) {
    const int bh = blockIdx.x;
    const int b = bh / NH_;
    float* row = scores + (size_t)bh * S_ * S_;   // row 0
    __shared__ float red[256];
    const int tid = threadIdx.x;
    float m = -INFINITY;
    for (int k = tid; k < S_; k += 256) m = fmaxf(m, row[k]);
    red[tid] = m;
    __syncthreads();
    for (int s = 128; s > 0; s >>= 1) {
        if (tid < s) red[tid] = fmaxf(red[tid], red[tid + s]);
        __syncthreads();
    }
    const float mx = red[0];
    for (int k = tid; k < S_; k += 256) {
        float mf = (k == 0) ? 0.f : mask[(size_t)b * SM1 + k - 1];
        if (mf < 0.5f) row[k] += mx * 0.25f;
    }
}

// ---------------------------------------------------------------------------
// Fused softmax + ctx, restructured:
//  * 128-row q-tile (grid 5 x BH), 8x4 microtile in sweep2 (32 FMA/kk/thread)
//  * sweep1: row stats, 2 rows in flight per warp (halves latency convoy)
//  * sweep2: register-prefetch double buffering (T14): issue chunk c+1 global
//    loads during chunk c compute; probs global store moved OUT of the
//    barrier-to-barrier section so it drains under compute.
// ---------------------------------------------------------------------------
__global__ __launch_bounds__(256) void softmax_ctx_kernel(
        float* __restrict__ scores,      // in: raw scores; out: probs (weights)
        const float* __restrict__ v,
        float* __restrict__ ctx,         // (B,S,H) layout
        float* __restrict__ col0) {
    const int bh = blockIdx.y;
    const int qbase = blockIdx.x * 128;
    const int b = bh / NH_, h = bh - b * NH_;
    __shared__ float Ps[32][132];   // [k][q]
    __shared__ float Vs[32][64];    // [k][d]
    __shared__ float rmax[128], rinv[128];
    const int tid = threadIdx.x;
    const int lane = tid & 63, wid = tid >> 6;
    float* sb = scores + (size_t)bh * S_ * S_;

    if (tid < 128) { rmax[tid] = 0.f; rinv[tid] = 0.f; }
    __syncthreads();

    // ---- Sweep 1: row max + sum(exp), col0 snapshot; 2 rows in flight ----
    for (int rr = wid * 2; rr < 128; rr += 8) {
        float vals[2][10];
        int q0 = qbase + rr, q1 = q0 + 1;
        const float* r0p = sb + (size_t)q0 * S_;
        const float* r1p = sb + (size_t)q1 * S_;
        bool ok0 = q0 < S_, ok1 = q1 < S_;
        #pragma unroll
        for (int i = 0; i < 10; ++i) {
            int kk = lane + i * 64;
            vals[0][i] = (ok0 && kk < S_) ? r0p[kk] : -INFINITY;
            vals[1][i] = (ok1 && kk < S_) ? r1p[kk] : -INFINITY;
        }
        #pragma unroll
        for (int u = 0; u < 2; ++u) {
            if (!(u ? ok1 : ok0)) continue;
            float mx = -INFINITY;
            #pragma unroll
            for (int i = 0; i < 10; ++i) mx = fmaxf(mx, vals[u][i]);
            #pragma unroll
            for (int off = 32; off > 0; off >>= 1) mx = fmaxf(mx, __shfl_xor(mx, off, 64));
            float sum = 0.f;
            #pragma unroll
            for (int i = 0; i < 10; ++i)
                sum += (lane + i * 64 < S_) ? expf(vals[u][i] - mx) : 0.f;
            #pragma unroll
            for (int off = 32; off > 0; off >>= 1) sum += __shfl_xor(sum, off, 64);
            if (lane == 0) {
                rmax[rr + u] = mx;
                rinv[rr + u] = 1.f / sum;
                col0[(size_t)bh * S_ + qbase + rr + u] = vals[u][0];
            }
        }
    }
    __syncthreads();

    // per-thread row stats for the 16 staged elements (r fixed per l)
    float myMax[16], myInv[16];
    #pragma unroll
    for (int l = 0; l < 16; ++l) {
        int r = (tid >> 5) + l * 8;        // 0..127
        myMax[l] = rmax[r];
        myInv[l] = rinv[r];
    }

    // ---- Sweep 2: double-buffered probs+V staging, 8x4 microtile ----
    const int tx = tid & 15, ty = tid >> 4;
    float c[2][4][4] = {};                  // rows: rg*64+ty*4+i, cols: tx*4+j
    const float* vb = v + (size_t)bh * S_ * DH_;
    const int NC = (S_ + 31) / 32;          // 20

    float pref_s[16], pref_v[8], p_reg[16];

    // preload chunk 0
    {
        #pragma unroll
        for (int l = 0; l < 16; ++l) {
            int idx = tid + l * 256;
            int kk = idx & 31, r = idx >> 5;
            int qq = qbase + r;
            pref_s[l] = (qq < S_ && kk < S_) ? sb[(size_t)qq * S_ + kk] : -INFINITY;
        }
        #pragma unroll
        for (int l = 0; l < 8; ++l) {
            int idx = tid + l * 256;
            int d = idx & 63, r = idx >> 6;
            pref_v[l] = (r < S_) ? vb[((size_t)r << 6) + d] : 0.f;
        }
    }

    for (int cch = 0; cch < NC; ++cch) {
        const int k0 = cch * 32;
        __syncthreads();                    // previous compute done, LDS free
        // write staged chunk to LDS (exp applied here)
        #pragma unroll
        for (int l = 0; l < 16; ++l) {
            int idx = tid + l * 256;
            int kk = idx & 31, r = idx >> 5;
            float p = expf(pref_s[l] - myMax[l]) * myInv[l];
            p_reg[l] = p;
            Ps[kk][r] = p;
        }
        #pragma unroll
        for (int l = 0; l < 8; ++l) {
            int idx = tid + l * 256;
            int d = idx & 63, r = idx >> 6;
            Vs[r][d] = pref_v[l];
        }
        __syncthreads();                    // LDS ready

        // probs global store (drains under compute, not at a barrier)
        #pragma unroll
        for (int l = 0; l < 16; ++l) {
            int idx = tid + l * 256;
            int kk = idx & 31, r = idx >> 5;
            int qq = qbase + r, k2 = k0 + kk;
            if (qq < S_ && k2 < S_) sb[(size_t)qq * S_ + k2] = p_reg[l];
        }
        // prefetch next chunk (latency hidden under compute below)
        if (cch + 1 < NC) {
            const int kn = k0 + 32;
            #pragma unroll
            for (int l = 0; l < 16; ++l) {
                int idx = tid + l * 256;
                int kk = idx & 31, r = idx >> 5;
                int qq = qbase + r, k2 = kn + kk;
                pref_s[l] = (qq < S_ && k2 < S_) ? sb[(size_t)qq * S_ + k2] : -INFINITY;
            }
            #pragma unroll
            for (int l = 0; l < 8; ++l) {
                int idx = tid + l * 256;
                int d = idx & 63, r = idx >> 6;
                int k2 = kn + r;
                pref_v[l] = (k2 < S_) ? vb[((size_t)k2 << 6) + d] : 0.f;
            }
        }
        // compute
        #pragma unroll 8
        for (int kk = 0; kk < 32; ++kk) {
            float a[2][4], bv[4];
            *(float4*)a[0] = *(const float4*)&Ps[kk][ty * 4];
            *(float4*)a[1] = *(const float4*)&Ps[kk][64 + ty * 4];
            *(float4*)bv   = *(const float4*)&Vs[kk][tx * 4];
            #pragma unroll
            for (int rg = 0; rg < 2; ++rg)
                #pragma unroll
                for (int i = 0; i < 4; ++i)
                    #pragma unroll
                    for (int j = 0; j < 4; ++j)
                        c[rg][i][j] += a[rg][i] * bv[j];
        }
    }

    #pragma unroll
    for (int rg = 0; rg < 2; ++rg) {
        #pragma unroll
        for (int i = 0; i < 4; ++i) {
            int qq = qbase + rg * 64 + ty * 4 + i;
            if (qq >= S_) continue;
            *(float4*)&ctx[((size_t)(b * S_ + qq)) * H_ + h * DH_ + tx * 4] =
                *(float4*)c[rg][i];
        }
    }
}

// ---------------------------------------------------------------------------
// sm2[bh, q] = softmax over q of col0[bh, :].
// ---------------------------------------------------------------------------
__global__ void sm2_kernel(const float* __restrict__ col0, float* __restrict__ out) {
    const int bh = blockIdx.x;
    const float* c = col0 + (size_t)bh * S_;
    __shared__ float red[256];
    const int tid = threadIdx.x;
    float m = -INFINITY;
    for (int q = tid; q < S_; q += 256) m = fmaxf(m, c[q]);
    red[tid] = m;
    __syncthreads();
    for (int s = 128; s > 0; s >>= 1) {
        if (tid < s) red[tid] = fmaxf(red[tid], red[tid + s]);
        __syncthreads();
    }
    const float mx = red[0];
    __syncthreads();
    float sum = 0.f;
    for (int q = tid; q < S_; q += 256) sum += expf(c[q] - mx);
    red[tid] = sum;
    __syncthreads();
    for (int s = 128; s > 0; s >>= 1) {
        if (tid < s) red[tid] += red[tid + s];
        __syncthreads();
    }
    const float inv = 1.f / red[0];
    for (int q = tid; q < S_; q += 256) out[(size_t)bh * S_ + q] = expf(c[q] - mx) * inv;
}

// ---------------------------------------------------------------------------
extern "C" void kernel_launch(void* const* d_in, const int* in_sizes, int n_in,
                              void* d_out, int out_size, void* d_ws, size_t ws_size,
                              hipStream_t stream) {
    const float* hs   = (const float*)d_in[0];
    const float* mask = (const float*)d_in[1];
    const float* Wq   = (const float*)d_in[2];
    const float* bq   = (const float*)d_in[3];
    const float* Wk   = (const float*)d_in[4];
    const float* bk   = (const float*)d_in[5];
    const float* Wv   = (const float*)d_in[6];
    const float* bv   = (const float*)d_in[7];
    const float* Wo   = (const float*)d_in[8];
    const float* bo   = (const float*)d_in[9];

    float* out     = (float*)d_out;                              // (B,S,H)
    float* weights = out + (size_t)B_ * S_ * H_;                 // (B,NH,S,S)
    float* sm2     = weights + (size_t)BH_ * S_ * S_;            // (B,NH,S)

    float* ws    = (float*)d_ws;
    const size_t headSz = (size_t)BH_ * S_ * DH_;                // 7,692,288
    float* q_ws  = ws;
    float* k_ws  = q_ws + headSz;
    float* v_ws  = k_ws + headSz;
    float* col0  = v_ws + headSz;                                // BH*S floats
    float* ctx_ws = q_ws;                                        // Q dead after scores

    dim3 gemmGrid(6, 79);       // N=768/128, ceil(10016/128)
    gemm_bias<1><<<gemmGrid, 256, 0, stream>>>(hs, Wq, bq, q_ws, M_, H_, H_);
    gemm_bias<1><<<gemmGrid, 256, 0, stream>>>(hs, Wk, bk, k_ws, M_, H_, H_);
    gemm_bias<1><<<gemmGrid, 256, 0, stream>>>(hs, Wv, bv, v_ws, M_, H_, H_);

    scores_kernel<<<dim3(5, 5, BH_), 256, 0, stream>>>(q_ws, k_ws, weights);
    row0_kernel<<<BH_, 256, 0, stream>>>(weights, mask);
    softmax_ctx_kernel<<<dim3(5, BH_), 256, 0, stream>>>(weights, v_ws, ctx_ws, col0);
    sm2_kernel<<<BH_, 256, 0, stream>>>(col0, sm2);

    gemm_bias<0><<<gemmGrid, 256, 0, stream>>>(ctx_ws, Wo, bo, out, M_, H_, H_);
}

// Round 3
// 1494.014 us; speedup vs baseline: 1.3337x; 1.0389x over previous
//
#include <hip/hip_runtime.h>
#include <hip/hip_bf16.h>
#include <math.h>

#define B_  16
#define S_  626
#define H_  768
#define NH_ 12
#define DH_ 64
#define BH_ (B_*NH_)          // 192
#define M_  (B_*S_)           // 10016
#define SM1 (S_-1)            // 625
#define PSTRIDE 640           // per-(bh,ktile) partial-stat row stride
#define NKT 5                 // ceil(626/128) k-tiles in scores

// ---------------------------------------------------------------------------
// Generic C = A(MxK) @ W(KxN) + bias(N), fp32.
// 128 rows x 64 cols block tile (grid 12x79 = 948 blocks: ~15 waves/CU vs the
// old 474-block config's ~8), 8x4 microtile (32 FMA : 3 ds_read_b128),
// K-chunk 32, register-prefetch double buffering on the global loads.
// MODE 0: C row-major. MODE 1: head-scatter (col tile lies within one head).
// ---------------------------------------------------------------------------
template<int MODE>
__global__ __launch_bounds__(256) void gemm_bias(
        const float* __restrict__ A, const float* __restrict__ W,
        const float* __restrict__ bias, float* __restrict__ out,
        int M, int N, int K) {
    __shared__ float As[32][132];   // [k][m] transposed A tile
    __shared__ float Bs[32][64];    // [k][n]
    const int tid = threadIdx.x;
    const int tx = tid & 15, ty = tid >> 4;
    const int rowBase = blockIdx.y * 128;
    const int colBase = blockIdx.x * 64;
    float c[2][4][4] = {};

    float4 prefA[4], prefB[2];
    // preload chunk 0
    #pragma unroll
    for (int l = 0; l < 4; ++l) {
        int idx = tid + l * 256;
        int kk4 = (idx & 7) << 2, m = idx >> 3;
        int row = rowBase + m;
        prefA[l] = (row < M) ? *(const float4*)&A[(size_t)row * K + kk4]
                             : make_float4(0.f, 0.f, 0.f, 0.f);
    }
    #pragma unroll
    for (int l = 0; l < 2; ++l) {
        int idx = tid + l * 256;
        int n = (idx & 15) << 2, kk = idx >> 4;
        prefB[l] = *(const float4*)&W[(size_t)kk * N + colBase + n];
    }

    for (int k0 = 0; k0 < K; k0 += 32) {
        __syncthreads();                 // prev compute done, LDS reusable
        #pragma unroll
        for (int l = 0; l < 4; ++l) {
            int idx = tid + l * 256;
            int kk4 = (idx & 7) << 2, m = idx >> 3;
            As[kk4 + 0][m] = prefA[l].x;
            As[kk4 + 1][m] = prefA[l].y;
            As[kk4 + 2][m] = prefA[l].z;
            As[kk4 + 3][m] = prefA[l].w;
        }
        #pragma unroll
        for (int l = 0; l < 2; ++l) {
            int idx = tid + l * 256;
            int n = (idx & 15) << 2, kk = idx >> 4;
            *(float4*)&Bs[kk][n] = prefB[l];
        }
        __syncthreads();
        // prefetch next chunk (hidden under compute)
        if (k0 + 32 < K) {
            const int kn = k0 + 32;
            #pragma unroll
            for (int l = 0; l < 4; ++l) {
                int idx = tid + l * 256;
                int kk4 = (idx & 7) << 2, m = idx >> 3;
                int row = rowBase + m;
                prefA[l] = (row < M) ? *(const float4*)&A[(size_t)row * K + kn + kk4]
                                     : make_float4(0.f, 0.f, 0.f, 0.f);
            }
            #pragma unroll
            for (int l = 0; l < 2; ++l) {
                int idx = tid + l * 256;
                int n = (idx & 15) << 2, kk = idx >> 4;
                prefB[l] = *(const float4*)&W[(size_t)(kn + kk) * N + colBase + n];
            }
        }
        #pragma unroll 8
        for (int kk = 0; kk < 32; ++kk) {
            float a[2][4], b[4];
            *(float4*)a[0] = *(const float4*)&As[kk][ty * 4];
            *(float4*)a[1] = *(const float4*)&As[kk][64 + ty * 4];
            *(float4*)b    = *(const float4*)&Bs[kk][tx * 4];
            #pragma unroll
            for (int rg = 0; rg < 2; ++rg)
                #pragma unroll
                for (int i = 0; i < 4; ++i)
                    #pragma unroll
                    for (int j = 0; j < 4; ++j)
                        c[rg][i][j] += a[rg][i] * b[j];
        }
    }

    #pragma unroll
    for (int rg = 0; rg < 2; ++rg) {
        #pragma unroll
        for (int i = 0; i < 4; ++i) {
            int row = rowBase + rg * 64 + ty * 4 + i;
            if (row >= M) continue;
            int col = colBase + tx * 4;
            float4 val;
            val.x = c[rg][i][0] + bias[col + 0];
            val.y = c[rg][i][1] + bias[col + 1];
            val.z = c[rg][i][2] + bias[col + 2];
            val.w = c[rg][i][3] + bias[col + 3];
            if (MODE == 0) {
                *(float4*)&out[(size_t)row * N + col] = val;
            } else {
                int b_ = row / S_, s_ = row - b_ * S_;
                int h_ = col >> 6, d_ = col & 63;
                *(float4*)&out[(((size_t)(b_ * NH_ + h_) * S_ + s_) << 6) + d_] = val;
            }
        }
    }
}

// ---------------------------------------------------------------------------
// scores[bh, q, k] = (Q . K) * 0.125, 128x128 tile, 8x8 microtile.
// NEW: emits per-(row, k-tile) online-softmax partials (m_t, l_t) so the
// softmax/ctx kernel never has to re-read scores for row stats.
// ---------------------------------------------------------------------------
__global__ __launch_bounds__(256) void scores_kernel(
        const float* __restrict__ q, const float* __restrict__ k,
        float* __restrict__ scores,
        float* __restrict__ part_m, float* __restrict__ part_l) {
    const int bh = blockIdx.z;
    const int qbase = blockIdx.y * 128;
    const int kbase = blockIdx.x * 128;
    __shared__ float Qs[32][132];
    __shared__ float Ks[32][132];
    const int tid = threadIdx.x;
    const int tx = tid & 15, ty = tid >> 4;
    const float* qb = q + (size_t)bh * S_ * DH_;
    const float* kb = k + (size_t)bh * S_ * DH_;
    float c[2][2][4][4] = {};

    for (int k0 = 0; k0 < DH_; k0 += 32) {
        #pragma unroll
        for (int l = 0; l < 4; ++l) {
            int idx = tid + l * 256;
            int kk4 = (idx & 7) << 2, m = idx >> 3;
            float4 v4 = make_float4(0.f, 0.f, 0.f, 0.f);
            if (qbase + m < S_)
                v4 = *(const float4*)&qb[((size_t)(qbase + m) << 6) + k0 + kk4];
            Qs[kk4 + 0][m] = v4.x; Qs[kk4 + 1][m] = v4.y;
            Qs[kk4 + 2][m] = v4.z; Qs[kk4 + 3][m] = v4.w;
            float4 w4 = make_float4(0.f, 0.f, 0.f, 0.f);
            if (kbase + m < S_)
                w4 = *(const float4*)&kb[((size_t)(kbase + m) << 6) + k0 + kk4];
            Ks[kk4 + 0][m] = w4.x; Ks[kk4 + 1][m] = w4.y;
            Ks[kk4 + 2][m] = w4.z; Ks[kk4 + 3][m] = w4.w;
        }
        __syncthreads();
        #pragma unroll 8
        for (int kk = 0; kk < 32; ++kk) {
            float a[2][4], b[2][4];
            *(float4*)a[0] = *(const float4*)&Qs[kk][ty * 4];
            *(float4*)a[1] = *(const float4*)&Qs[kk][64 + ty * 4];
            *(float4*)b[0] = *(const float4*)&Ks[kk][tx * 4];
            *(float4*)b[1] = *(const float4*)&Ks[kk][64 + tx * 4];
            #pragma unroll
            for (int rg = 0; rg < 2; ++rg)
                #pragma unroll
                for (int cg = 0; cg < 2; ++cg)
                    #pragma unroll
                    for (int i = 0; i < 4; ++i)
                        #pragma unroll
                        for (int j = 0; j < 4; ++j)
                            c[rg][cg][i][j] += a[rg][i] * b[cg][j];
        }
        __syncthreads();
    }

    // write scores + per-row partial stats over this 128-col slice
    #pragma unroll
    for (int rg = 0; rg < 2; ++rg) {
        #pragma unroll
        for (int i = 0; i < 4; ++i) {
            int qi = qbase + rg * 64 + ty * 4 + i;
            float vv[2][4];
            float mloc = -INFINITY;
            #pragma unroll
            for (int cg = 0; cg < 2; ++cg)
                #pragma unroll
                for (int j = 0; j < 4; ++j) {
                    int ki = kbase + cg * 64 + tx * 4 + j;
                    float sv = c[rg][cg][i][j] * 0.125f;
                    vv[cg][j] = sv;
                    if (ki < S_) mloc = fmaxf(mloc, sv);
                }
            if (qi < S_) {
                float* row = scores + ((size_t)bh * S_ + qi) * S_;
                #pragma unroll
                for (int cg = 0; cg < 2; ++cg) {
                    int ki = kbase + cg * 64 + tx * 4;
                    if (ki + 3 < S_) {
                        *(float4*)&row[ki] = *(float4*)vv[cg];
                    } else {
                        #pragma unroll
                        for (int j = 0; j < 4; ++j)
                            if (ki + j < S_) row[ki + j] = vv[cg][j];
                    }
                }
            }
            // cross-tx reduce (16-lane groups; xor masks stay in-group)
            #pragma unroll
            for (int off = 1; off < 16; off <<= 1)
                mloc = fmaxf(mloc, __shfl_xor(mloc, off, 64));
            float lloc = 0.f;
            #pragma unroll
            for (int cg = 0; cg < 2; ++cg)
                #pragma unroll
                for (int j = 0; j < 4; ++j) {
                    int ki = kbase + cg * 64 + tx * 4 + j;
                    if (ki < S_) lloc += expf(vv[cg][j] - mloc);
                }
            #pragma unroll
            for (int off = 1; off < 16; off <<= 1)
                lloc += __shfl_xor(lloc, off, 64);
            if (tx == 0 && qi < S_) {
                size_t pidx = ((size_t)bh * NKT + blockIdx.x) * PSTRIDE + qi;
                part_m[pidx] = mloc;
                part_l[pidx] = lloc;
            }
        }
    }
}

// ---------------------------------------------------------------------------
// stats_kernel (one block per bh): row-0 mask adjustment + adjusted row-0
// stats, then combines per-k-tile partials into rmax/rinv for q>=1, and
// snapshots col0 (adjusted for q=0, raw otherwise) for sm2.
// ---------------------------------------------------------------------------
__global__ __launch_bounds__(256) void stats_kernel(
        float* __restrict__ scores, const float* __restrict__ mask,
        const float* __restrict__ part_m, const float* __restrict__ part_l,
        float* __restrict__ rmax_g, float* __restrict__ rinv_g,
        float* __restrict__ col0) {
    const int bh = blockIdx.x;
    const int b = bh / NH_;
    float* row = scores + (size_t)bh * S_ * S_;   // row 0
    __shared__ float red[256];
    const int tid = threadIdx.x;

    // pass 1: raw row-0 max, values kept in registers
    float v0[3];
    float m = -INFINITY;
    #pragma unroll
    for (int i = 0; i < 3; ++i) {
        int kk = tid + i * 256;
        v0[i] = (kk < S_) ? row[kk] : -INFINITY;
        m = fmaxf(m, v0[i]);
    }
    red[tid] = m;
    __syncthreads();
    for (int s = 128; s > 0; s >>= 1) {
        if (tid < s) red[tid] = fmaxf(red[tid], red[tid + s]);
        __syncthreads();
    }
    const float mx = red[0];
    __syncthreads();

    // pass 2: apply mask adjustment (in regs + memory), adjusted max
    float m2 = -INFINITY;
    #pragma unroll
    for (int i = 0; i < 3; ++i) {
        int kk = tid + i * 256;
        if (kk < S_) {
            float mf = (kk == 0) ? 0.f : mask[(size_t)b * SM1 + kk - 1];
            float nv = (mf < 0.5f) ? v0[i] + mx * 0.25f : v0[i];
            v0[i] = nv;
            row[kk] = nv;
            m2 = fmaxf(m2, nv);
        }
    }
    red[tid] = m2;
    __syncthreads();
    for (int s = 128; s > 0; s >>= 1) {
        if (tid < s) red[tid] = fmaxf(red[tid], red[tid + s]);
        __syncthreads();
    }
    const float mxa = red[0];
    __syncthreads();

    // pass 3: adjusted sum(exp)
    float sum = 0.f;
    #pragma unroll
    for (int i = 0; i < 3; ++i) {
        int kk = tid + i * 256;
        if (kk < S_) sum += expf(v0[i] - mxa);
    }
    red[tid] = sum;
    __syncthreads();
    for (int s = 128; s > 0; s >>= 1) {
        if (tid < s) red[tid] += red[tid + s];
        __syncthreads();
    }
    if (tid == 0) {
        rmax_g[(size_t)bh * PSTRIDE] = mxa;
        rinv_g[(size_t)bh * PSTRIDE] = 1.f / red[0];
        col0[(size_t)bh * S_] = v0[0];           // adjusted s(0,0)
    }

    // combine partials for q = 1..S-1 ; snapshot raw col0
    for (int q = tid; q < S_; q += 256) {
        if (q == 0) continue;
        float mM = -INFINITY;
        float pm[NKT];
        #pragma unroll
        for (int t = 0; t < NKT; ++t) {
            pm[t] = part_m[((size_t)bh * NKT + t) * PSTRIDE + q];
            mM = fmaxf(mM, pm[t]);
        }
        float l = 0.f;
        #pragma unroll
        for (int t = 0; t < NKT; ++t)
            l += part_l[((size_t)bh * NKT + t) * PSTRIDE + q] * expf(pm[t] - mM);
        rmax_g[(size_t)bh * PSTRIDE + q] = mM;
        rinv_g[(size_t)bh * PSTRIDE + q] = 1.f / l;
        col0[(size_t)bh * S_ + q] = row[(size_t)q * S_];   // raw s(q,0)
    }
}

// ---------------------------------------------------------------------------
// softmax_ctx: sweep1 removed (stats come from rmax_g/rinv_g). Single pass:
// read raw scores, write probs, accumulate ctx = P @ V. Register-prefetch
// double-buffered staging, 8x4 microtile on a 128-row q-tile.
// ---------------------------------------------------------------------------
__global__ __launch_bounds__(256) void softmax_ctx_kernel(
        float* __restrict__ scores,      // in: raw scores; out: probs (weights)
        const float* __restrict__ v,
        float* __restrict__ ctx,         // (B,S,H) layout
        const float* __restrict__ rmax_g, const float* __restrict__ rinv_g) {
    const int bh = blockIdx.y;
    const int qbase = blockIdx.x * 128;
    const int b = bh / NH_, h = bh - b * NH_;
    __shared__ float Ps[32][132];   // [k][q]
    __shared__ float Vs[32][64];    // [k][d]
    __shared__ float rmaxS[128], rinvS[128];
    const int tid = threadIdx.x;
    float* sb = scores + (size_t)bh * S_ * S_;

    if (tid < 128) {
        int q = qbase + tid;
        rmaxS[tid] = (q < S_) ? rmax_g[(size_t)bh * PSTRIDE + q] : 0.f;
        rinvS[tid] = (q < S_) ? rinv_g[(size_t)bh * PSTRIDE + q] : 0.f;
    }
    __syncthreads();

    float myMax[16], myInv[16];
    #pragma unroll
    for (int l = 0; l < 16; ++l) {
        int r = (tid >> 5) + l * 8;        // 0..127
        myMax[l] = rmaxS[r];
        myInv[l] = rinvS[r];
    }

    const int tx = tid & 15, ty = tid >> 4;
    float c[2][4][4] = {};
    const float* vb = v + (size_t)bh * S_ * DH_;
    const int NC = (S_ + 31) / 32;          // 20

    float pref_s[16], pref_v[8], p_reg[16];
    #pragma unroll
    for (int l = 0; l < 16; ++l) {
        int idx = tid + l * 256;
        int kk = idx & 31, r = idx >> 5;
        int qq = qbase + r;
        pref_s[l] = (qq < S_ && kk < S_) ? sb[(size_t)qq * S_ + kk] : -INFINITY;
    }
    #pragma unroll
    for (int l = 0; l < 8; ++l) {
        int idx = tid + l * 256;
        int d = idx & 63, r = idx >> 6;
        pref_v[l] = (r < S_) ? vb[((size_t)r << 6) + d] : 0.f;
    }

    for (int cch = 0; cch < NC; ++cch) {
        const int k0 = cch * 32;
        __syncthreads();                    // prev compute done
        #pragma unroll
        for (int l = 0; l < 16; ++l) {
            int idx = tid + l * 256;
            int kk = idx & 31, r = idx >> 5;
            float p = expf(pref_s[l] - myMax[l]) * myInv[l];
            p_reg[l] = p;
            Ps[kk][r] = p;
        }
        #pragma unroll
        for (int l = 0; l < 8; ++l) {
            int idx = tid + l * 256;
            int d = idx & 63, r = idx >> 6;
            Vs[r][d] = pref_v[l];
        }
        __syncthreads();                    // LDS ready

        #pragma unroll
        for (int l = 0; l < 16; ++l) {
            int idx = tid + l * 256;
            int kk = idx & 31, r = idx >> 5;
            int qq = qbase + r, k2 = k0 + kk;
            if (qq < S_ && k2 < S_) sb[(size_t)qq * S_ + k2] = p_reg[l];
        }
        if (cch + 1 < NC) {
            const int kn = k0 + 32;
            #pragma unroll
            for (int l = 0; l < 16; ++l) {
                int idx = tid + l * 256;
                int kk = idx & 31, r = idx >> 5;
                int qq = qbase + r, k2 = kn + kk;
                pref_s[l] = (qq < S_ && k2 < S_) ? sb[(size_t)qq * S_ + k2] : -INFINITY;
            }
            #pragma unroll
            for (int l = 0; l < 8; ++l) {
                int idx = tid + l * 256;
                int d = idx & 63, r = idx >> 6;
                int k2 = kn + r;
                pref_v[l] = (k2 < S_) ? vb[((size_t)k2 << 6) + d] : 0.f;
            }
        }
        #pragma unroll 8
        for (int kk = 0; kk < 32; ++kk) {
            float a[2][4], bv[4];
            *(float4*)a[0] = *(const float4*)&Ps[kk][ty * 4];
            *(float4*)a[1] = *(const float4*)&Ps[kk][64 + ty * 4];
            *(float4*)bv   = *(const float4*)&Vs[kk][tx * 4];
            #pragma unroll
            for (int rg = 0; rg < 2; ++rg)
                #pragma unroll
                for (int i = 0; i < 4; ++i)
                    #pragma unroll
                    for (int j = 0; j < 4; ++j)
                        c[rg][i][j] += a[rg][i] * bv[j];
        }
    }

    #pragma unroll
    for (int rg = 0; rg < 2; ++rg) {
        #pragma unroll
        for (int i = 0; i < 4; ++i) {
            int qq = qbase + rg * 64 + ty * 4 + i;
            if (qq >= S_) continue;
            *(float4*)&ctx[((size_t)(b * S_ + qq)) * H_ + h * DH_ + tx * 4] =
                *(float4*)c[rg][i];
        }
    }
}

// ---------------------------------------------------------------------------
// sm2[bh, q] = softmax over q of col0[bh, :].
// ---------------------------------------------------------------------------
__global__ void sm2_kernel(const float* __restrict__ col0, float* __restrict__ out) {
    const int bh = blockIdx.x;
    const float* c = col0 + (size_t)bh * S_;
    __shared__ float red[256];
    const int tid = threadIdx.x;
    float m = -INFINITY;
    for (int q = tid; q < S_; q += 256) m = fmaxf(m, c[q]);
    red[tid] = m;
    __syncthreads();
    for (int s = 128; s > 0; s >>= 1) {
        if (tid < s) red[tid] = fmaxf(red[tid], red[tid + s]);
        __syncthreads();
    }
    const float mx = red[0];
    __syncthreads();
    float sum = 0.f;
    for (int q = tid; q < S_; q += 256) sum += expf(c[q] - mx);
    red[tid] = sum;
    __syncthreads();
    for (int s = 128; s > 0; s >>= 1) {
        if (tid < s) red[tid] += red[tid + s];
        __syncthreads();
    }
    const float inv = 1.f / red[0];
    for (int q = tid; q < S_; q += 256) out[(size_t)bh * S_ + q] = expf(c[q] - mx) * inv;
}

// ---------------------------------------------------------------------------
extern "C" void kernel_launch(void* const* d_in, const int* in_sizes, int n_in,
                              void* d_out, int out_size, void* d_ws, size_t ws_size,
                              hipStream_t stream) {
    const float* hs   = (const float*)d_in[0];
    const float* mask = (const float*)d_in[1];
    const float* Wq   = (const float*)d_in[2];
    const float* bq   = (const float*)d_in[3];
    const float* Wk   = (const float*)d_in[4];
    const float* bk   = (const float*)d_in[5];
    const float* Wv   = (const float*)d_in[6];
    const float* bv   = (const float*)d_in[7];
    const float* Wo   = (const float*)d_in[8];
    const float* bo   = (const float*)d_in[9];

    float* out     = (float*)d_out;                              // (B,S,H)
    float* weights = out + (size_t)B_ * S_ * H_;                 // (B,NH,S,S)
    float* sm2     = weights + (size_t)BH_ * S_ * S_;            // (B,NH,S)

    float* ws    = (float*)d_ws;
    const size_t headSz = (size_t)BH_ * S_ * DH_;                // 7,692,288
    float* q_ws   = ws;
    float* k_ws   = q_ws + headSz;
    float* v_ws   = k_ws + headSz;
    float* col0   = v_ws + headSz;                               // BH*S
    float* rmax_g = col0 + (size_t)BH_ * S_;                     // BH*640
    float* rinv_g = rmax_g + (size_t)BH_ * PSTRIDE;              // BH*640
    float* part_m = rinv_g + (size_t)BH_ * PSTRIDE;              // BH*5*640
    float* part_l = part_m + (size_t)BH_ * NKT * PSTRIDE;        // BH*5*640
    float* ctx_ws = q_ws;                                        // Q dead after scores

    dim3 gemmGrid(12, 79);      // N=768/64, ceil(10016/128)
    gemm_bias<1><<<gemmGrid, 256, 0, stream>>>(hs, Wq, bq, q_ws, M_, H_, H_);
    gemm_bias<1><<<gemmGrid, 256, 0, stream>>>(hs, Wk, bk, k_ws, M_, H_, H_);
    gemm_bias<1><<<gemmGrid, 256, 0, stream>>>(hs, Wv, bv, v_ws, M_, H_, H_);

    scores_kernel<<<dim3(NKT, 5, BH_), 256, 0, stream>>>(q_ws, k_ws, weights,
                                                         part_m, part_l);
    stats_kernel<<<BH_, 256, 0, stream>>>(weights, mask, part_m, part_l,
                                          rmax_g, rinv_g, col0);
    sm2_kernel<<<BH_, 256, 0, stream>>>(col0, sm2);
    softmax_ctx_kernel<<<dim3(5, BH_), 256, 0, stream>>>(weights, v_ws, ctx_ws,
                                                         rmax_g, rinv_g);

    gemm_bias<0><<<gemmGrid, 256, 0, stream>>>(ctx_ws, Wo, bo, out, M_, H_, H_);
}

// Round 5
// 1152.595 us; speedup vs baseline: 1.7288x; 1.2962x over previous
//
#include <hip/hip_runtime.h>
#include <hip/hip_bf16.h>
#include <math.h>

#define B_  16
#define S_  626
#define H_  768
#define NH_ 12
#define DH_ 64
#define BH_ (B_*NH_)          // 192
#define M_  (B_*S_)           // 10016
#define SM1 (S_-1)            // 625
#define PSTRIDE 640           // per-(bh,ktile) partial-stat row stride
#define NKT 5                 // ceil(626/128) k-tiles in scores

typedef __attribute__((ext_vector_type(8))) short bf16x8;   // 8 bf16 (4 VGPRs)
typedef __attribute__((ext_vector_type(4))) float f32x4;    // MFMA accumulator

union U16 { uint4 u; bf16x8 v; };

// round-to-nearest-even fp32 -> bf16 (top 16 bits)
__device__ __forceinline__ uint rne16(uint u) {
    return (u + 0x7fffu + ((u >> 16) & 1u)) >> 16;
}
// pack x ~= hi + lo (both bf16) into one u32: hi in low half, lo in high half
__device__ __forceinline__ uint pack_bf16x2(float x) {
    uint hi = rne16(__float_as_uint(x));
    float r = x - __uint_as_float(hi << 16);
    uint lo = rne16(__float_as_uint(r));
    return hi | (lo << 16);
}

// ---------------------------------------------------------------------------
// pack fp32 -> (hi|lo) u32, elementwise (for hidden_states)
// ---------------------------------------------------------------------------
__global__ __launch_bounds__(256) void pack_kernel(const float* __restrict__ in,
                                                   uint* __restrict__ outp, int n4) {
    int i = blockIdx.x * 256 + threadIdx.x;
    const int stride = gridDim.x * 256;
    for (; i < n4; i += stride) {
        float4 v = *(const float4*)&in[(size_t)i * 4];
        uint4 p;
        p.x = pack_bf16x2(v.x); p.y = pack_bf16x2(v.y);
        p.z = pack_bf16x2(v.z); p.w = pack_bf16x2(v.w);
        *(uint4*)&outp[(size_t)i * 4] = p;
    }
}

// ---------------------------------------------------------------------------
// transpose + pack a 768x768 weight: Wt[n][k] = pack(W[k][n])
// ---------------------------------------------------------------------------
__global__ __launch_bounds__(256) void packT_kernel(const float* __restrict__ W,
                                                    uint* __restrict__ Wt) {
    __shared__ uint t[32][33];
    const int tid = threadIdx.x;
    const int tx = tid & 31, ty = tid >> 5;      // ty 0..7
    const int nb = blockIdx.x * 32, kb = blockIdx.y * 32;
    #pragma unroll
    for (int r = 0; r < 4; ++r) {
        int k = kb + ty + r * 8;
        t[ty + r * 8][tx] = pack_bf16x2(W[(size_t)k * H_ + nb + tx]);
    }
    __syncthreads();
    #pragma unroll
    for (int r = 0; r < 4; ++r) {
        int n = nb + ty + r * 8;
        Wt[(size_t)n * H_ + kb + tx] = t[tx][ty + r * 8];
    }
}

// ---------------------------------------------------------------------------
// MFMA split-bf16 GEMM: C = A(Mx768) @ W(768x768) + bias, fp32-accurate via
// bf16x3 (AhBh + AhBl + AlBh). A packed [m][k] u32(hi|lo); B packed TRANSPOSED
// [n][k]. 128x128 tile, 4 waves each computing a 64x64 quadrant as 4x4
// mfma_f32_16x16x32_bf16 fragments; K-chunk 32, reg-prefetch double buffer.
// Layouts: A-frag row=lane&15, k=(lane>>4)*8+i; B-frag col=lane&15, same k;
// D col=lane&15, row=(lane>>4)*4+reg  [verified m89].
// MODE 0: row-major out. MODE 1: head-scatter.
// ---------------------------------------------------------------------------
template<int MODE>
__global__ __launch_bounds__(256) void gemm_mfma(
        const uint* __restrict__ Ap, const uint* __restrict__ Bt,
        const float* __restrict__ bias, float* __restrict__ out, int M) {
    __shared__ uint As[128][36];    // [m][k] packed, pad 36 (144B: 16B-aligned rows)
    __shared__ uint Bs[128][36];    // [n][k] packed
    const int tid = threadIdx.x;
    const int lane = tid & 63, wave = tid >> 6;
    const int wr = (wave >> 1) * 64, wc = (wave & 1) * 64;
    const int rowBase = blockIdx.y * 128;
    const int colBase = blockIdx.x * 128;
    const int l15 = lane & 15, l4 = lane >> 4;

    f32x4 acc[4][4];
    #pragma unroll
    for (int i = 0; i < 4; ++i)
        #pragma unroll
        for (int j = 0; j < 4; ++j) acc[i][j] = (f32x4){0.f, 0.f, 0.f, 0.f};

    const int skq = (tid & 7) * 4;      // u32 col in LDS tile
    const int srow0 = tid >> 3;         // staging row, +32 per l

    uint4 pa[4], pb[4];
    #pragma unroll
    for (int l = 0; l < 4; ++l) {
        int row = srow0 + l * 32;
        int grow = rowBase + row;
        pa[l] = (grow < M) ? *(const uint4*)&Ap[(size_t)grow * H_ + skq]
                           : make_uint4(0u, 0u, 0u, 0u);
        pb[l] = *(const uint4*)&Bt[(size_t)(colBase + row) * H_ + skq];
    }

    for (int k0 = 0; k0 < H_; k0 += 32) {
        __syncthreads();
        #pragma unroll
        for (int l = 0; l < 4; ++l) {
            int row = srow0 + l * 32;
            *(uint4*)&As[row][skq] = pa[l];
            *(uint4*)&Bs[row][skq] = pb[l];
        }
        __syncthreads();
        if (k0 + 32 < H_) {
            #pragma unroll
            for (int l = 0; l < 4; ++l) {
                int row = srow0 + l * 32;
                int grow = rowBase + row;
                pa[l] = (grow < M)
                    ? *(const uint4*)&Ap[(size_t)grow * H_ + k0 + 32 + skq]
                    : make_uint4(0u, 0u, 0u, 0u);
                pb[l] = *(const uint4*)&Bt[(size_t)(colBase + row) * H_ + k0 + 32 + skq];
            }
        }
        // A fragments (hi & lo) for this wave's 64 rows
        bf16x8 ah[4], al[4];
        #pragma unroll
        for (int ai = 0; ai < 4; ++ai) {
            const uint* p = &As[wr + ai * 16 + l15][l4 * 8];
            uint4 x = *(const uint4*)p;
            uint4 y = *(const uint4*)(p + 4);
            U16 h, lo;
            h.u.x  = (x.x & 0xffffu) | (x.y << 16);
            h.u.y  = (x.z & 0xffffu) | (x.w << 16);
            h.u.z  = (y.x & 0xffffu) | (y.y << 16);
            h.u.w  = (y.z & 0xffffu) | (y.w << 16);
            lo.u.x = (x.x >> 16) | (x.y & 0xffff0000u);
            lo.u.y = (x.z >> 16) | (x.w & 0xffff0000u);
            lo.u.z = (y.x >> 16) | (y.y & 0xffff0000u);
            lo.u.w = (y.z >> 16) | (y.w & 0xffff0000u);
            ah[ai] = h.v; al[ai] = lo.v;
        }
        #pragma unroll
        for (int bj = 0; bj < 4; ++bj) {
            const uint* p = &Bs[wc + bj * 16 + l15][l4 * 8];
            uint4 x = *(const uint4*)p;
            uint4 y = *(const uint4*)(p + 4);
            U16 h, lo;
            h.u.x  = (x.x & 0xffffu) | (x.y << 16);
            h.u.y  = (x.z & 0xffffu) | (x.w << 16);
            h.u.z  = (y.x & 0xffffu) | (y.y << 16);
            h.u.w  = (y.z & 0xffffu) | (y.w << 16);
            lo.u.x = (x.x >> 16) | (x.y & 0xffff0000u);
            lo.u.y = (x.z >> 16) | (x.w & 0xffff0000u);
            lo.u.z = (y.x >> 16) | (y.y & 0xffff0000u);
            lo.u.w = (y.z >> 16) | (y.w & 0xffff0000u);
            bf16x8 bh = h.v, bl = lo.v;
            #pragma unroll
            for (int ai = 0; ai < 4; ++ai) {
                acc[ai][bj] = __builtin_amdgcn_mfma_f32_16x16x32_bf16(ah[ai], bh, acc[ai][bj], 0, 0, 0);
                acc[ai][bj] = __builtin_amdgcn_mfma_f32_16x16x32_bf16(ah[ai], bl, acc[ai][bj], 0, 0, 0);
                acc[ai][bj] = __builtin_amdgcn_mfma_f32_16x16x32_bf16(al[ai], bh, acc[ai][bj], 0, 0, 0);
            }
        }
    }

    #pragma unroll
    for (int ai = 0; ai < 4; ++ai) {
        #pragma unroll
        for (int r = 0; r < 4; ++r) {
            int grow = rowBase + wr + ai * 16 + l4 * 4 + r;
            if (grow >= M) continue;
            #pragma unroll
            for (int bj = 0; bj < 4; ++bj) {
                int gcol = colBase + wc + bj * 16 + l15;
                float val = acc[ai][bj][r] + bias[gcol];
                if (MODE == 0) {
                    out[(size_t)grow * H_ + gcol] = val;
                } else {
                    int b_ = grow / S_, s_ = grow - b_ * S_;
                    int h_ = gcol >> 6, d_ = gcol & 63;
                    out[(((size_t)(b_ * NH_ + h_) * S_ + s_) << 6) + d_] = val;
                }
            }
        }
    }
}

// ---------------------------------------------------------------------------
// scores[bh, q, k] = (Q . K) * 0.125, 128x128 tile, 8x8 microtile.
// Emits per-(row, k-tile) online-softmax partials (m_t, l_t). (unchanged R3)
// ---------------------------------------------------------------------------
__global__ __launch_bounds__(256) void scores_kernel(
        const float* __restrict__ q, const float* __restrict__ k,
        float* __restrict__ scores,
        float* __restrict__ part_m, float* __restrict__ part_l) {
    const int bh = blockIdx.z;
    const int qbase = blockIdx.y * 128;
    const int kbase = blockIdx.x * 128;
    __shared__ float Qs[32][132];
    __shared__ float Ks[32][132];
    const int tid = threadIdx.x;
    const int tx = tid & 15, ty = tid >> 4;
    const float* qb = q + (size_t)bh * S_ * DH_;
    const float* kb = k + (size_t)bh * S_ * DH_;
    float c[2][2][4][4] = {};

    for (int k0 = 0; k0 < DH_; k0 += 32) {
        #pragma unroll
        for (int l = 0; l < 4; ++l) {
            int idx = tid + l * 256;
            int kk4 = (idx & 7) << 2, m = idx >> 3;
            float4 v4 = make_float4(0.f, 0.f, 0.f, 0.f);
            if (qbase + m < S_)
                v4 = *(const float4*)&qb[((size_t)(qbase + m) << 6) + k0 + kk4];
            Qs[kk4 + 0][m] = v4.x; Qs[kk4 + 1][m] = v4.y;
            Qs[kk4 + 2][m] = v4.z; Qs[kk4 + 3][m] = v4.w;
            float4 w4 = make_float4(0.f, 0.f, 0.f, 0.f);
            if (kbase + m < S_)
                w4 = *(const float4*)&kb[((size_t)(kbase + m) << 6) + k0 + kk4];
            Ks[kk4 + 0][m] = w4.x; Ks[kk4 + 1][m] = w4.y;
            Ks[kk4 + 2][m] = w4.z; Ks[kk4 + 3][m] = w4.w;
        }
        __syncthreads();
        #pragma unroll 8
        for (int kk = 0; kk < 32; ++kk) {
            float a[2][4], b[2][4];
            *(float4*)a[0] = *(const float4*)&Qs[kk][ty * 4];
            *(float4*)a[1] = *(const float4*)&Qs[kk][64 + ty * 4];
            *(float4*)b[0] = *(const float4*)&Ks[kk][tx * 4];
            *(float4*)b[1] = *(const float4*)&Ks[kk][64 + tx * 4];
            #pragma unroll
            for (int rg = 0; rg < 2; ++rg)
                #pragma unroll
                for (int cg = 0; cg < 2; ++cg)
                    #pragma unroll
                    for (int i = 0; i < 4; ++i)
                        #pragma unroll
                        for (int j = 0; j < 4; ++j)
                            c[rg][cg][i][j] += a[rg][i] * b[cg][j];
        }
        __syncthreads();
    }

    #pragma unroll
    for (int rg = 0; rg < 2; ++rg) {
        #pragma unroll
        for (int i = 0; i < 4; ++i) {
            int qi = qbase + rg * 64 + ty * 4 + i;
            float vv[2][4];
            float mloc = -INFINITY;
            #pragma unroll
            for (int cg = 0; cg < 2; ++cg)
                #pragma unroll
                for (int j = 0; j < 4; ++j) {
                    int ki = kbase + cg * 64 + tx * 4 + j;
                    float sv = c[rg][cg][i][j] * 0.125f;
                    vv[cg][j] = sv;
                    if (ki < S_) mloc = fmaxf(mloc, sv);
                }
            if (qi < S_) {
                float* row = scores + ((size_t)bh * S_ + qi) * S_;
                #pragma unroll
                for (int cg = 0; cg < 2; ++cg) {
                    int ki = kbase + cg * 64 + tx * 4;
                    if (ki + 3 < S_) {
                        *(float4*)&row[ki] = *(float4*)vv[cg];
                    } else {
                        #pragma unroll
                        for (int j = 0; j < 4; ++j)
                            if (ki + j < S_) row[ki + j] = vv[cg][j];
                    }
                }
            }
            #pragma unroll
            for (int off = 1; off < 16; off <<= 1)
                mloc = fmaxf(mloc, __shfl_xor(mloc, off, 64));
            float lloc = 0.f;
            #pragma unroll
            for (int cg = 0; cg < 2; ++cg)
                #pragma unroll
                for (int j = 0; j < 4; ++j) {
                    int ki = kbase + cg * 64 + tx * 4 + j;
                    if (ki < S_) lloc += expf(vv[cg][j] - mloc);
                }
            #pragma unroll
            for (int off = 1; off < 16; off <<= 1)
                lloc += __shfl_xor(lloc, off, 64);
            if (tx == 0 && qi < S_) {
                size_t pidx = ((size_t)bh * NKT + blockIdx.x) * PSTRIDE + qi;
                part_m[pidx] = mloc;
                part_l[pidx] = lloc;
            }
        }
    }
}

// ---------------------------------------------------------------------------
// stats_kernel (unchanged R3): row-0 mask adjust + combine partials -> rmax/rinv
// ---------------------------------------------------------------------------
__global__ __launch_bounds__(256) void stats_kernel(
        float* __restrict__ scores, const float* __restrict__ mask,
        const float* __restrict__ part_m, const float* __restrict__ part_l,
        float* __restrict__ rmax_g, float* __restrict__ rinv_g,
        float* __restrict__ col0) {
    const int bh = blockIdx.x;
    const int b = bh / NH_;
    float* row = scores + (size_t)bh * S_ * S_;   // row 0
    __shared__ float red[256];
    const int tid = threadIdx.x;

    float v0[3];
    float m = -INFINITY;
    #pragma unroll
    for (int i = 0; i < 3; ++i) {
        int kk = tid + i * 256;
        v0[i] = (kk < S_) ? row[kk] : -INFINITY;
        m = fmaxf(m, v0[i]);
    }
    red[tid] = m;
    __syncthreads();
    for (int s = 128; s > 0; s >>= 1) {
        if (tid < s) red[tid] = fmaxf(red[tid], red[tid + s]);
        __syncthreads();
    }
    const float mx = red[0];
    __syncthreads();

    float m2 = -INFINITY;
    #pragma unroll
    for (int i = 0; i < 3; ++i) {
        int kk = tid + i * 256;
        if (kk < S_) {
            float mf = (kk == 0) ? 0.f : mask[(size_t)b * SM1 + kk - 1];
            float nv = (mf < 0.5f) ? v0[i] + mx * 0.25f : v0[i];
            v0[i] = nv;
            row[kk] = nv;
            m2 = fmaxf(m2, nv);
        }
    }
    red[tid] = m2;
    __syncthreads();
    for (int s = 128; s > 0; s >>= 1) {
        if (tid < s) red[tid] = fmaxf(red[tid], red[tid + s]);
        __syncthreads();
    }
    const float mxa = red[0];
    __syncthreads();

    float sum = 0.f;
    #pragma unroll
    for (int i = 0; i < 3; ++i) {
        int kk = tid + i * 256;
        if (kk < S_) sum += expf(v0[i] - mxa);
    }
    red[tid] = sum;
    __syncthreads();
    for (int s = 128; s > 0; s >>= 1) {
        if (tid < s) red[tid] += red[tid + s];
        __syncthreads();
    }
    if (tid == 0) {
        rmax_g[(size_t)bh * PSTRIDE] = mxa;
        rinv_g[(size_t)bh * PSTRIDE] = 1.f / red[0];
        col0[(size_t)bh * S_] = v0[0];
    }

    for (int q = tid; q < S_; q += 256) {
        if (q == 0) continue;
        float mM = -INFINITY;
        float pm[NKT];
        #pragma unroll
        for (int t = 0; t < NKT; ++t) {
            pm[t] = part_m[((size_t)bh * NKT + t) * PSTRIDE + q];
            mM = fmaxf(mM, pm[t]);
        }
        float l = 0.f;
        #pragma unroll
        for (int t = 0; t < NKT; ++t)
            l += part_l[((size_t)bh * NKT + t) * PSTRIDE + q] * expf(pm[t] - mM);
        rmax_g[(size_t)bh * PSTRIDE + q] = mM;
        rinv_g[(size_t)bh * PSTRIDE + q] = 1.f / l;
        col0[(size_t)bh * S_ + q] = row[(size_t)q * S_];
    }
}

// ---------------------------------------------------------------------------
// softmax_ctx (R3 structure) — epilogue writes ctx PACKED (hi|lo u32) so the
// out-projection MFMA GEMM consumes it directly.
// ---------------------------------------------------------------------------
__global__ __launch_bounds__(256) void softmax_ctx_kernel(
        float* __restrict__ scores,
        const float* __restrict__ v,
        uint* __restrict__ ctxp,         // (B,S,H) packed bf16x2
        const float* __restrict__ rmax_g, const float* __restrict__ rinv_g) {
    const int bh = blockIdx.y;
    const int qbase = blockIdx.x * 128;
    const int b = bh / NH_, h = bh - b * NH_;
    __shared__ float Ps[32][132];
    __shared__ float Vs[32][64];
    __shared__ float rmaxS[128], rinvS[128];
    const int tid = threadIdx.x;
    float* sb = scores + (size_t)bh * S_ * S_;

    if (tid < 128) {
        int q = qbase + tid;
        rmaxS[tid] = (q < S_) ? rmax_g[(size_t)bh * PSTRIDE + q] : 0.f;
        rinvS[tid] = (q < S_) ? rinv_g[(size_t)bh * PSTRIDE + q] : 0.f;
    }
    __syncthreads();

    float myMax[16], myInv[16];
    #pragma unroll
    for (int l = 0; l < 16; ++l) {
        int r = (tid >> 5) + l * 8;
        myMax[l] = rmaxS[r];
        myInv[l] = rinvS[r];
    }

    const int tx = tid & 15, ty = tid >> 4;
    float c[2][4][4] = {};
    const float* vb = v + (size_t)bh * S_ * DH_;
    const int NC = (S_ + 31) / 32;

    float pref_s[16], pref_v[8], p_reg[16];
    #pragma unroll
    for (int l = 0; l < 16; ++l) {
        int idx = tid + l * 256;
        int kk = idx & 31, r = idx >> 5;
        int qq = qbase + r;
        pref_s[l] = (qq < S_ && kk < S_) ? sb[(size_t)qq * S_ + kk] : -INFINITY;
    }
    #pragma unroll
    for (int l = 0; l < 8; ++l) {
        int idx = tid + l * 256;
        int d = idx & 63, r = idx >> 6;
        pref_v[l] = (r < S_) ? vb[((size_t)r << 6) + d] : 0.f;
    }

    for (int cch = 0; cch < NC; ++cch) {
        const int k0 = cch * 32;
        __syncthreads();
        #pragma unroll
        for (int l = 0; l < 16; ++l) {
            int idx = tid + l * 256;
            int kk = idx & 31, r = idx >> 5;
            float p = expf(pref_s[l] - myMax[l]) * myInv[l];
            p_reg[l] = p;
            Ps[kk][r] = p;
        }
        #pragma unroll
        for (int l = 0; l < 8; ++l) {
            int idx = tid + l * 256;
            int d = idx & 63, r = idx >> 6;
            Vs[r][d] = pref_v[l];
        }
        __syncthreads();

        #pragma unroll
        for (int l = 0; l < 16; ++l) {
            int idx = tid + l * 256;
            int kk = idx & 31, r = idx >> 5;
            int qq = qbase + r, k2 = k0 + kk;
            if (qq < S_ && k2 < S_) sb[(size_t)qq * S_ + k2] = p_reg[l];
        }
        if (cch + 1 < NC) {
            const int kn = k0 + 32;
            #pragma unroll
            for (int l = 0; l < 16; ++l) {
                int idx = tid + l * 256;
                int kk = idx & 31, r = idx >> 5;
                int qq = qbase + r, k2 = kn + kk;
                pref_s[l] = (qq < S_ && k2 < S_) ? sb[(size_t)qq * S_ + k2] : -INFINITY;
            }
            #pragma unroll
            for (int l = 0; l < 8; ++l) {
                int idx = tid + l * 256;
                int d = idx & 63, r = idx >> 6;
                int k2 = kn + r;
                pref_v[l] = (k2 < S_) ? vb[((size_t)k2 << 6) + d] : 0.f;
            }
        }
        #pragma unroll 8
        for (int kk = 0; kk < 32; ++kk) {
            float a[2][4], bv[4];
            *(float4*)a[0] = *(const float4*)&Ps[kk][ty * 4];
            *(float4*)a[1] = *(const float4*)&Ps[kk][64 + ty * 4];
            *(float4*)bv   = *(const float4*)&Vs[kk][tx * 4];
            #pragma unroll
            for (int rg = 0; rg < 2; ++rg)
                #pragma unroll
                for (int i = 0; i < 4; ++i)
                    #pragma unroll
                    for (int j = 0; j < 4; ++j)
                        c[rg][i][j] += a[rg][i] * bv[j];
        }
    }

    #pragma unroll
    for (int rg = 0; rg < 2; ++rg) {
        #pragma unroll
        for (int i = 0; i < 4; ++i) {
            int qq = qbase + rg * 64 + ty * 4 + i;
            if (qq >= S_) continue;
            uint4 pv;
            pv.x = pack_bf16x2(c[rg][i][0]);
            pv.y = pack_bf16x2(c[rg][i][1]);
            pv.z = pack_bf16x2(c[rg][i][2]);
            pv.w = pack_bf16x2(c[rg][i][3]);
            *(uint4*)&ctxp[((size_t)(b * S_ + qq)) * H_ + h * DH_ + tx * 4] = pv;
        }
    }
}

// ---------------------------------------------------------------------------
// sm2[bh, q] = softmax over q of col0[bh, :].
// ---------------------------------------------------------------------------
__global__ void sm2_kernel(const float* __restrict__ col0, float* __restrict__ out) {
    const int bh = blockIdx.x;
    const float* c = col0 + (size_t)bh * S_;
    __shared__ float red[256];
    const int tid = threadIdx.x;
    float m = -INFINITY;
    for (int q = tid; q < S_; q += 256) m = fmaxf(m, c[q]);
    red[tid] = m;
    __syncthreads();
    for (int s = 128; s > 0; s >>= 1) {
        if (tid < s) red[tid] = fmaxf(red[tid], red[tid + s]);
        __syncthreads();
    }
    const float mx = red[0];
    __syncthreads();
    float sum = 0.f;
    for (int q = tid; q < S_; q += 256) sum += expf(c[q] - mx);
    red[tid] = sum;
    __syncthreads();
    for (int s = 128; s > 0; s >>= 1) {
        if (tid < s) red[tid] += red[tid + s];
        __syncthreads();
    }
    const float inv = 1.f / red[0];
    for (int q = tid; q < S_; q += 256) out[(size_t)bh * S_ + q] = expf(c[q] - mx) * inv;
}

// ---------------------------------------------------------------------------
extern "C" void kernel_launch(void* const* d_in, const int* in_sizes, int n_in,
                              void* d_out, int out_size, void* d_ws, size_t ws_size,
                              hipStream_t stream) {
    const float* hs   = (const float*)d_in[0];
    const float* mask = (const float*)d_in[1];
    const float* Wq   = (const float*)d_in[2];
    const float* bq   = (const float*)d_in[3];
    const float* Wk   = (const float*)d_in[4];
    const float* bk   = (const float*)d_in[5];
    const float* Wv   = (const float*)d_in[6];
    const float* bv   = (const float*)d_in[7];
    const float* Wo   = (const float*)d_in[8];
    const float* bo   = (const float*)d_in[9];

    float* out     = (float*)d_out;                              // (B,S,H)
    float* weights = out + (size_t)B_ * S_ * H_;                 // (B,NH,S,S)
    float* sm2     = weights + (size_t)BH_ * S_ * S_;            // (B,NH,S)

    float* ws    = (float*)d_ws;
    const size_t headSz = (size_t)BH_ * S_ * DH_;                // 7,692,288
    float* q_ws   = ws;
    float* k_ws   = q_ws + headSz;
    float* v_ws   = k_ws + headSz;
    float* col0   = v_ws + headSz;                               // BH*S
    float* rmax_g = col0 + (size_t)BH_ * S_;                     // BH*640
    float* rinv_g = rmax_g + (size_t)BH_ * PSTRIDE;              // BH*640
    float* part_m = rinv_g + (size_t)BH_ * PSTRIDE;              // BH*5*640
    float* part_l = part_m + (size_t)BH_ * NKT * PSTRIDE;        // BH*5*640
    uint*  ctxp   = (uint*)q_ws;                                 // Q dead after scores

    // Packed QKV staging lives in the weights-output region: hs_p/wq/wk/wv are
    // dead before scores_kernel overwrites that region. Wo's packed copy must
    // SURVIVE scores (it's read by the final GEMM), so it aliases part_m (ws),
    // which is dead after stats_kernel — packT(Wo) launches after stats.
    uint* hs_p = (uint*)weights;                                 // M*H u32
    uint* wqt  = hs_p + (size_t)M_ * H_;
    uint* wkt  = wqt + (size_t)H_ * H_;
    uint* wvt  = wkt + (size_t)H_ * H_;
    uint* wot  = (uint*)part_m;                                  // H*H u32 (2.4MB < 4.9MB)

    pack_kernel<<<2048, 256, 0, stream>>>(hs, hs_p, (M_ * H_) / 4);
    packT_kernel<<<dim3(24, 24), 256, 0, stream>>>(Wq, wqt);
    packT_kernel<<<dim3(24, 24), 256, 0, stream>>>(Wk, wkt);
    packT_kernel<<<dim3(24, 24), 256, 0, stream>>>(Wv, wvt);

    dim3 gemmGrid(6, 79);       // N=768/128, ceil(10016/128)
    gemm_mfma<1><<<gemmGrid, 256, 0, stream>>>(hs_p, wqt, bq, q_ws, M_);
    gemm_mfma<1><<<gemmGrid, 256, 0, stream>>>(hs_p, wkt, bk, k_ws, M_);
    gemm_mfma<1><<<gemmGrid, 256, 0, stream>>>(hs_p, wvt, bv, v_ws, M_);

    scores_kernel<<<dim3(NKT, 5, BH_), 256, 0, stream>>>(q_ws, k_ws, weights,
                                                         part_m, part_l);
    stats_kernel<<<BH_, 256, 0, stream>>>(weights, mask, part_m, part_l,
                                          rmax_g, rinv_g, col0);
    packT_kernel<<<dim3(24, 24), 256, 0, stream>>>(Wo, wot);   // part_m now dead
    sm2_kernel<<<BH_, 256, 0, stream>>>(col0, sm2);
    softmax_ctx_kernel<<<dim3(5, BH_), 256, 0, stream>>>(weights, v_ws, ctxp,
                                                         rmax_g, rinv_g);

    gemm_mfma<0><<<gemmGrid, 256, 0, stream>>>(ctxp, wot, bo, out, M_);
}